// Round 1
// baseline (229.015 us; speedup 1.0000x reference)
//
#include <hip/hip_runtime.h>

// Problem constants
#define Bb 2
#define Ww 2048
#define Cc 512
#define Nn 8
#define Kk 64
// rows per tensor (b,w flattened)
#define ROWS 4096            // Bb*Ww
#define HALFN 2016           // K*(K+1)/2 - K

// ---------------------------------------------------------------------------
// Kernel 1: LayerNorm of x1 and x2 -> Xn (8192 x 512), rows 0..4095 = x1n,
// rows 4096..8191 = x2n.
// ---------------------------------------------------------------------------
__global__ __launch_bounds__(256) void ln_kernel(const float* __restrict__ x1,
                                                 const float* __restrict__ x2,
                                                 const float* __restrict__ gamma,
                                                 const float* __restrict__ beta,
                                                 float* __restrict__ Xn) {
    int row = blockIdx.x;  // 0..8191
    const float* src = (row < ROWS) ? (x1 + (size_t)row * Cc)
                                    : (x2 + (size_t)(row - ROWS) * Cc);
    int t = threadIdx.x;
    float2 v = *(const float2*)&src[t * 2];
    float s  = v.x + v.y;
    float sq = v.x * v.x + v.y * v.y;
    // wave (64-lane) reduction
    #pragma unroll
    for (int off = 32; off > 0; off >>= 1) {
        s  += __shfl_down(s, off);
        sq += __shfl_down(sq, off);
    }
    __shared__ float ls[8], lq[8];
    int wave = t >> 6, lane = t & 63;
    if (lane == 0) { ls[wave] = s; lq[wave] = sq; }
    __syncthreads();
    if (t == 0) {
        float S = 0.f, Q = 0.f;
        #pragma unroll
        for (int i = 0; i < 4; i++) { S += ls[i]; Q += lq[i]; }
        float mu  = S * (1.0f / Cc);
        float var = Q * (1.0f / Cc) - mu * mu;
        ls[4] = mu;
        lq[4] = rsqrtf(var + 1e-5f);
    }
    __syncthreads();
    float mu = ls[4], rs = lq[4];
    float2 g  = *(const float2*)&gamma[t * 2];
    float2 bb = *(const float2*)&beta[t * 2];
    float2 o;
    o.x = (v.x - mu) * rs * g.x + bb.x;
    o.y = (v.y - mu) * rs * g.y + bb.y;
    *(float2*)&Xn[(size_t)row * Cc + t * 2] = o;
}

// ---------------------------------------------------------------------------
// Kernel 2: PP = Xn @ Pw  (8192 x 512) where Pw[c][n*64+k] = proj[n,c,k].
// Tiled 64x64, BK=16, 256 threads, 4x4 micro-tile per thread.
// grid: (8 col-tiles [== head], 128 row-tiles)
// ---------------------------------------------------------------------------
__global__ __launch_bounds__(256) void gemm_proj(const float* __restrict__ Xn,
                                                 const float* __restrict__ proj,
                                                 float* __restrict__ PP) {
    __shared__ float As[16][68];   // transposed A tile, padded
    __shared__ float Bs[16][64];
    const int t = threadIdx.x;
    const int head = blockIdx.x;          // col tile == head (BN=64=K)
    const int m0 = blockIdx.y * 64;
    const int tm = t >> 4, tn = t & 15;
    const int la_r = t >> 2, la_c = (t & 3) * 4;   // A tile: 64 rows x 16 cols
    const int lb_r = t >> 4, lb_c = (t & 15) * 4;  // B tile: 16 rows x 64 cols
    float acc[4][4] = {};

    for (int kt = 0; kt < Cc; kt += 16) {
        float4 av = *(const float4*)&Xn[(size_t)(m0 + la_r) * Cc + kt + la_c];
        float4 bv = *(const float4*)&proj[(size_t)head * (Cc * Kk) +
                                          (size_t)(kt + lb_r) * Kk + lb_c];
        As[la_c + 0][la_r] = av.x;
        As[la_c + 1][la_r] = av.y;
        As[la_c + 2][la_r] = av.z;
        As[la_c + 3][la_r] = av.w;
        *(float4*)&Bs[lb_r][lb_c] = bv;
        __syncthreads();
        #pragma unroll
        for (int k = 0; k < 16; k++) {
            float4 a4 = *(const float4*)&As[k][tm * 4];
            float4 b4 = *(const float4*)&Bs[k][tn * 4];
            float am[4] = {a4.x, a4.y, a4.z, a4.w};
            float bn[4] = {b4.x, b4.y, b4.z, b4.w};
            #pragma unroll
            for (int i = 0; i < 4; i++)
                #pragma unroll
                for (int j = 0; j < 4; j++)
                    acc[i][j] = fmaf(am[i], bn[j], acc[i][j]);
        }
        __syncthreads();
    }
    #pragma unroll
    for (int i = 0; i < 4; i++) {
        float4 o = {acc[i][0], acc[i][1], acc[i][2], acc[i][3]};
        *(float4*)&PP[(size_t)(m0 + tm * 4 + i) * Cc + head * 64 + tn * 4] = o;
    }
}

// ---------------------------------------------------------------------------
// Kernel 3: G[b,n][j,kk] = sum_v p2[b,n,v,j] * p1[b,n,v,kk]   (64x64 per b,n)
// Split over W in chunks of 256, accumulate via atomicAdd (S pre-zeroed).
// grid: (16 [b*8+n], 8 [w-chunk])
// ---------------------------------------------------------------------------
__global__ __launch_bounds__(256) void s_kernel(const float* __restrict__ PP,
                                                float* __restrict__ S) {
    __shared__ float p1s[64][64];
    __shared__ float p2s[64][64];
    const int bn = blockIdx.x;
    const int b = bn >> 3, n = bn & 7;
    const int v0 = blockIdx.y * 256;
    const int t = threadIdx.x;
    const int tj = t >> 4, tk = t & 15;
    const int lr = t >> 4, lc = (t & 15) * 4;
    const float* p1base = PP + (size_t)(b * Ww) * Cc + n * 64;
    const float* p2base = PP + (size_t)(ROWS + b * Ww) * Cc + n * 64;
    float acc[4][4] = {};

    for (int sub = 0; sub < 256; sub += 64) {
        #pragma unroll
        for (int i = 0; i < 4; i++) {
            int v = v0 + sub + lr + i * 16;
            *(float4*)&p1s[lr + i * 16][lc] = *(const float4*)&p1base[(size_t)v * Cc + lc];
            *(float4*)&p2s[lr + i * 16][lc] = *(const float4*)&p2base[(size_t)v * Cc + lc];
        }
        __syncthreads();
        #pragma unroll 4
        for (int v = 0; v < 64; v++) {
            float4 a4 = *(const float4*)&p2s[v][tj * 4];
            float4 b4 = *(const float4*)&p1s[v][tk * 4];
            float am[4] = {a4.x, a4.y, a4.z, a4.w};
            float bm[4] = {b4.x, b4.y, b4.z, b4.w};
            #pragma unroll
            for (int i = 0; i < 4; i++)
                #pragma unroll
                for (int j = 0; j < 4; j++)
                    acc[i][j] = fmaf(am[i], bm[j], acc[i][j]);
        }
        __syncthreads();
    }
    float* Sb = S + (size_t)bn * 64 * 64;
    #pragma unroll
    for (int i = 0; i < 4; i++)
        #pragma unroll
        for (int j = 0; j < 4; j++)
            atomicAdd(&Sb[(tj * 4 + i) * 64 + tk * 4 + j], acc[i][j]);
}

// ---------------------------------------------------------------------------
// Kernel 4: build metric M_n, T = M @ G, U[b][(n*64+k)][c'] = sum_kk T[k][kk]*Wm[c'][n*64+kk]
// grid: (16 [b*8+n], 4 [c'-chunk of 128])
// ---------------------------------------------------------------------------
__global__ __launch_bounds__(256) void tu_kernel(const float* __restrict__ S,
                                                 const float* __restrict__ halves,
                                                 const float* __restrict__ diagonals,
                                                 const float* __restrict__ Wm,
                                                 float* __restrict__ U) {
    __shared__ float Ms[64][65];
    __shared__ float Gs[64][65];
    __shared__ float Ts[64][65];
    const int bn = blockIdx.x;
    const int b = bn >> 3, n = bn & 7;
    const int t = threadIdx.x;

    // build metric: strict upper from halves (mirrored), diag from diagonals
    for (int idx = t; idx < 4096; idx += 256) {
        int r = idx >> 6, c = idx & 63;
        float val;
        if (r == c) {
            val = diagonals[n * 64 + r];
        } else {
            int rr = (r < c) ? r : c;
            int cc = (r < c) ? c : r;
            // triu_indices(64,1) row-major flat index
            int h = rr * 63 - (rr * (rr - 1)) / 2 + (cc - rr - 1);
            val = halves[n * HALFN + h];
        }
        Ms[r][c] = val;
    }
    for (int idx = t; idx < 4096; idx += 256) {
        Gs[idx >> 6][idx & 63] = S[(size_t)bn * 4096 + idx];
    }
    __syncthreads();

    // T = M @ G (64x64)
    {
        const int tk = t >> 4, tkk = t & 15;
        float acc[4][4] = {};
        for (int j = 0; j < 64; j++) {
            float m[4], g[4];
            #pragma unroll
            for (int i = 0; i < 4; i++) m[i] = Ms[tk * 4 + i][j];
            #pragma unroll
            for (int l = 0; l < 4; l++) g[l] = Gs[j][tkk * 4 + l];
            #pragma unroll
            for (int i = 0; i < 4; i++)
                #pragma unroll
                for (int l = 0; l < 4; l++)
                    acc[i][l] = fmaf(m[i], g[l], acc[i][l]);
        }
        #pragma unroll
        for (int i = 0; i < 4; i++)
            #pragma unroll
            for (int l = 0; l < 4; l++)
                Ts[tk * 4 + i][tkk * 4 + l] = acc[i][l];
    }
    __syncthreads();

    // U[k][c'] = sum_kk T[k][kk] * Wm[c'][n*64+kk] for c' in this chunk
    const int c0 = blockIdx.y * 128;
    for (int iter = 0; iter < 32; iter++) {
        int flat = iter * 256 + t;          // 8192 = 64 k * 128 c
        int k = flat >> 7;
        int c = c0 + (flat & 127);
        const float* wrow = &Wm[(size_t)c * Cc + n * 64];
        float acc = 0.f;
        #pragma unroll
        for (int kk = 0; kk < 64; kk += 4) {
            float4 w4 = *(const float4*)&wrow[kk];
            acc = fmaf(Ts[k][kk + 0], w4.x, acc);
            acc = fmaf(Ts[k][kk + 1], w4.y, acc);
            acc = fmaf(Ts[k][kk + 2], w4.z, acc);
            acc = fmaf(Ts[k][kk + 3], w4.w, acc);
        }
        U[(size_t)b * (Cc * Cc) + (size_t)(n * 64 + k) * Cc + c] = acc;
    }
}

// ---------------------------------------------------------------------------
// Kernel 5: out[b] = PP1[b] (2048x512) @ U[b] (512x512) + b_mixer
// grid: (8 col-tiles, 32 row-tiles, 2 batch)
// ---------------------------------------------------------------------------
__global__ __launch_bounds__(256) void gemm_out(const float* __restrict__ PP,
                                                const float* __restrict__ U,
                                                const float* __restrict__ bmix,
                                                float* __restrict__ out) {
    __shared__ float As[16][68];
    __shared__ float Bs[16][64];
    const int t = threadIdx.x;
    const int b = blockIdx.z;
    const int n0 = blockIdx.x * 64;
    const int m0 = blockIdx.y * 64;
    const int tm = t >> 4, tn = t & 15;
    const int la_r = t >> 2, la_c = (t & 3) * 4;
    const int lb_r = t >> 4, lb_c = (t & 15) * 4;
    const float* A  = PP + (size_t)(b * Ww) * Cc;
    const float* Bm = U + (size_t)b * (Cc * Cc);
    float acc[4][4] = {};

    for (int kt = 0; kt < Cc; kt += 16) {
        float4 av = *(const float4*)&A[(size_t)(m0 + la_r) * Cc + kt + la_c];
        float4 bv = *(const float4*)&Bm[(size_t)(kt + lb_r) * Cc + n0 + lb_c];
        As[la_c + 0][la_r] = av.x;
        As[la_c + 1][la_r] = av.y;
        As[la_c + 2][la_r] = av.z;
        As[la_c + 3][la_r] = av.w;
        *(float4*)&Bs[lb_r][lb_c] = bv;
        __syncthreads();
        #pragma unroll
        for (int k = 0; k < 16; k++) {
            float4 a4 = *(const float4*)&As[k][tm * 4];
            float4 b4 = *(const float4*)&Bs[k][tn * 4];
            float am[4] = {a4.x, a4.y, a4.z, a4.w};
            float bn[4] = {b4.x, b4.y, b4.z, b4.w};
            #pragma unroll
            for (int i = 0; i < 4; i++)
                #pragma unroll
                for (int j = 0; j < 4; j++)
                    acc[i][j] = fmaf(am[i], bn[j], acc[i][j]);
        }
        __syncthreads();
    }
    float4 bias = *(const float4*)&bmix[n0 + tn * 4];
    #pragma unroll
    for (int i = 0; i < 4; i++) {
        float4 o;
        o.x = acc[i][0] + bias.x;
        o.y = acc[i][1] + bias.y;
        o.z = acc[i][2] + bias.z;
        o.w = acc[i][3] + bias.w;
        *(float4*)&out[(size_t)(b * Ww + m0 + tm * 4 + i) * Cc + n0 + tn * 4] = o;
    }
}

// ---------------------------------------------------------------------------
extern "C" void kernel_launch(void* const* d_in, const int* in_sizes, int n_in,
                              void* d_out, int out_size, void* d_ws, size_t ws_size,
                              hipStream_t stream) {
    (void)in_sizes; (void)n_in; (void)out_size; (void)ws_size;
    const float* x1        = (const float*)d_in[0];
    const float* x2        = (const float*)d_in[1];
    const float* gamma     = (const float*)d_in[2];
    const float* beta      = (const float*)d_in[3];
    const float* proj      = (const float*)d_in[4];
    const float* halves    = (const float*)d_in[5];
    const float* diagonals = (const float*)d_in[6];
    const float* Wm        = (const float*)d_in[7];
    const float* bmix      = (const float*)d_in[8];
    float* out = (float*)d_out;

    float* ws = (float*)d_ws;
    float* Xn = ws;                          // 8192*512 = 4,194,304 f
    float* PP = Xn + (size_t)8192 * 512;     // 4,194,304 f
    float* S  = PP + (size_t)8192 * 512;     // 16*64*64 = 65,536 f
    float* U  = S + 65536;                   // 2*512*512 = 524,288 f
    // total ~36 MB of workspace

    hipMemsetAsync(S, 0, 65536 * sizeof(float), stream);
    ln_kernel<<<dim3(8192), 256, 0, stream>>>(x1, x2, gamma, beta, Xn);
    gemm_proj<<<dim3(8, 128), 256, 0, stream>>>(Xn, proj, PP);
    s_kernel<<<dim3(16, 8), 256, 0, stream>>>(PP, S);
    tu_kernel<<<dim3(16, 4), 256, 0, stream>>>(S, halves, diagonals, Wm, U);
    gemm_out<<<dim3(8, 32, 2), 256, 0, stream>>>(PP, U, bmix, out);
}

// Round 2
// 184.586 us; speedup vs baseline: 1.2407x; 1.2407x over previous
//
#include <hip/hip_runtime.h>

typedef unsigned short u16;
typedef __attribute__((ext_vector_type(8))) short short8;   // 8 x bf16 (4 VGPRs)
typedef __attribute__((ext_vector_type(4))) float f32x4;

#define HALFN 2016

__device__ __forceinline__ u16 f2b(float x) {
    union { float f; unsigned u; } v; v.f = x;
    return (u16)(v.u >> 16);                 // truncation toward zero: remainder < ulp
}
__device__ __forceinline__ float b2f(u16 h) {
    union { float f; unsigned u; } v; v.u = ((unsigned)h) << 16;
    return v.f;
}

__device__ __forceinline__ void gll16(const void* g, void* s) {
    __builtin_amdgcn_global_load_lds(
        (const __attribute__((address_space(1))) unsigned int*)g,
        (__attribute__((address_space(3))) unsigned int*)s, 16, 0, 0);
}

// ---------------------------------------------------------------------------
// Kernel 1: LayerNorm -> bf16 hi/lo split, rows 0..4095 = x1n, 4096..8191 = x2n
// ---------------------------------------------------------------------------
__global__ __launch_bounds__(256) void ln_kernel(const float* __restrict__ x1,
                                                 const float* __restrict__ x2,
                                                 const float* __restrict__ gamma,
                                                 const float* __restrict__ beta,
                                                 u16* __restrict__ Xh,
                                                 u16* __restrict__ Xl) {
    int row = blockIdx.x;  // 0..8191
    const float* src = (row < 4096) ? (x1 + (size_t)row * 512)
                                    : (x2 + (size_t)(row - 4096) * 512);
    int t = threadIdx.x;
    float2 v = *(const float2*)&src[t * 2];
    float s  = v.x + v.y;
    float sq = v.x * v.x + v.y * v.y;
    #pragma unroll
    for (int off = 32; off > 0; off >>= 1) {
        s  += __shfl_down(s, off);
        sq += __shfl_down(sq, off);
    }
    __shared__ float ls[8], lq[8];
    int wave = t >> 6, lane = t & 63;
    if (lane == 0) { ls[wave] = s; lq[wave] = sq; }
    __syncthreads();
    if (t == 0) {
        float S = 0.f, Q = 0.f;
        #pragma unroll
        for (int i = 0; i < 4; i++) { S += ls[i]; Q += lq[i]; }
        float mu  = S * (1.0f / 512.0f);
        float var = Q * (1.0f / 512.0f) - mu * mu;
        ls[4] = mu;
        lq[4] = rsqrtf(var + 1e-5f);
    }
    __syncthreads();
    float mu = ls[4], rs = lq[4];
    float2 g  = *(const float2*)&gamma[t * 2];
    float2 bb = *(const float2*)&beta[t * 2];
    float o0 = (v.x - mu) * rs * g.x + bb.x;
    float o1 = (v.y - mu) * rs * g.y + bb.y;
    u16 h0 = f2b(o0), h1 = f2b(o1);
    u16 l0 = f2b(o0 - b2f(h0)), l1 = f2b(o1 - b2f(h1));
    ushort2 H; H.x = h0; H.y = h1;
    ushort2 L; L.x = l0; L.y = l1;
    *(ushort2*)&Xh[(size_t)row * 512 + t * 2] = H;
    *(ushort2*)&Xl[(size_t)row * 512 + t * 2] = L;
}

// ---------------------------------------------------------------------------
// Kernel 2: transpose+split proj[n][c][k] -> PwT hi/lo [(n*64+k)][c]
// grid: (8 heads, 8 c-chunks of 64)
// ---------------------------------------------------------------------------
__global__ __launch_bounds__(256) void prep_pw(const float* __restrict__ proj,
                                               u16* __restrict__ PwTh,
                                               u16* __restrict__ PwTl) {
    __shared__ float tile[64][65];
    const int n = blockIdx.x, c0 = blockIdx.y * 64;
    const int t = threadIdx.x;
    #pragma unroll
    for (int i = 0; i < 4; i++) {
        int flat = i * 256 + t;          // 1024 float4 = 64c x 16(k/4)
        int c = flat >> 4, k4 = (flat & 15) * 4;
        float4 v = *(const float4*)&proj[(size_t)n * 32768 + (size_t)(c0 + c) * 64 + k4];
        tile[c][k4 + 0] = v.x; tile[c][k4 + 1] = v.y;
        tile[c][k4 + 2] = v.z; tile[c][k4 + 3] = v.w;
    }
    __syncthreads();
    #pragma unroll
    for (int i = 0; i < 16; i++) {
        int flat = i * 256 + t;          // 4096 = 64k x 64c
        int k = flat >> 6, c = flat & 63;
        float v = tile[c][k];
        u16 h = f2b(v), lo = f2b(v - b2f(h));
        size_t o = (size_t)(n * 64 + k) * 512 + c0 + c;
        PwTh[o] = h; PwTl[o] = lo;
    }
}

// ---------------------------------------------------------------------------
// MFMA bf16x3 GEMM core: C128x128 tile, BK=32, A=[m][k] hi/lo, B=[n][k] hi/lo,
// K=512, ld=512.  XOR-swizzled LDS (no padding - global_load_lds needs
// contiguity); fragment ds_read_b128 is 2-way (free) by construction.
// ---------------------------------------------------------------------------
__device__ __forceinline__ void gemm_core(const u16* __restrict__ Ah,
                                          const u16* __restrict__ Al,
                                          const u16* __restrict__ Bh,
                                          const u16* __restrict__ Bl,
                                          int m0, int n0, u16* lds,
                                          f32x4 (&acc)[4][4]) {
    const int t = threadIdx.x;
    const int lane = t & 63;
    const int w = t >> 6, wm = w & 1, wn = w >> 1;
    const int fr = lane & 15, q = lane >> 4;

    int aoff[4], boff[4];
    #pragma unroll
    for (int i = 0; i < 4; i++) {
        int r = wm * 64 + i * 16 + fr;
        aoff[i] = r * 32 + ((q ^ ((r >> 1) & 3)) * 8);
        r = wn * 64 + i * 16 + fr;
        boff[i] = r * 32 + ((q ^ ((r >> 1) & 3)) * 8);
    }

    for (int kt = 0; kt < 512; kt += 32) {
        #pragma unroll
        for (int qi = 0; qi < 2; qi++) {
            int o = qi * 4096 + t * 16;          // byte offset in 8 KB comp tile
            int r = o >> 6;                      // tile row (64 B rows)
            int kc = ((o >> 4) & 3) ^ ((r >> 1) & 3);
            size_t gA = (size_t)(m0 + r) * 512 + kt + kc * 8;
            size_t gB = (size_t)(n0 + r) * 512 + kt + kc * 8;
            int le = o >> 1;                     // elem offset
            gll16(Ah + gA, lds + le);
            gll16(Al + gA, lds + 4096 + le);
            gll16(Bh + gB, lds + 8192 + le);
            gll16(Bl + gB, lds + 12288 + le);
        }
        __syncthreads();
        short8 afh[4], afl[4], bfh[4], bfl[4];
        #pragma unroll
        for (int i = 0; i < 4; i++) {
            afh[i] = *(const short8*)(lds + aoff[i]);
            afl[i] = *(const short8*)(lds + 4096 + aoff[i]);
            bfh[i] = *(const short8*)(lds + 8192 + boff[i]);
            bfl[i] = *(const short8*)(lds + 12288 + boff[i]);
        }
        #pragma unroll
        for (int i = 0; i < 4; i++)
            #pragma unroll
            for (int j = 0; j < 4; j++) {
                acc[i][j] = __builtin_amdgcn_mfma_f32_16x16x32_bf16(afh[i], bfh[j], acc[i][j], 0, 0, 0);
                acc[i][j] = __builtin_amdgcn_mfma_f32_16x16x32_bf16(afh[i], bfl[j], acc[i][j], 0, 0, 0);
                acc[i][j] = __builtin_amdgcn_mfma_f32_16x16x32_bf16(afl[i], bfh[j], acc[i][j], 0, 0, 0);
            }
        __syncthreads();
    }
}

// ---------------------------------------------------------------------------
// Kernel 3: PP = Xn @ Pw, output as bf16 hi/lo (fp32 = hi+lo reconstructed
// downstream).  grid (4, 64).
// ---------------------------------------------------------------------------
__global__ __launch_bounds__(256) void gemm_proj_mfma(const u16* __restrict__ Xh,
                                                      const u16* __restrict__ Xl,
                                                      const u16* __restrict__ PwTh,
                                                      const u16* __restrict__ PwTl,
                                                      u16* __restrict__ PPh,
                                                      u16* __restrict__ PPl) {
    __shared__ u16 lds[16384];
    f32x4 acc[4][4] = {};
    const int m0 = blockIdx.y * 128, n0 = blockIdx.x * 128;
    gemm_core(Xh, Xl, PwTh, PwTl, m0, n0, lds, acc);
    const int t = threadIdx.x, lane = t & 63, w = t >> 6, wm = w & 1, wn = w >> 1;
    #pragma unroll
    for (int i = 0; i < 4; i++) {
        int m = m0 + wm * 64 + i * 16 + (lane >> 4) * 4;
        #pragma unroll
        for (int j = 0; j < 4; j++) {
            int n = n0 + wn * 64 + j * 16 + (lane & 15);
            #pragma unroll
            for (int r = 0; r < 4; r++) {
                float v = acc[i][j][r];
                u16 h = f2b(v);
                u16 l = f2b(v - b2f(h));
                size_t o = (size_t)(m + r) * 512 + n;
                PPh[o] = h; PPl[o] = l;
            }
        }
    }
}

// ---------------------------------------------------------------------------
// Kernel 4: G[b,n] = P2^T P1 (64x64 per b,n), fp32, split-W + atomics.
// grid: (16, 8).  PP reconstructed as hi+lo.
// ---------------------------------------------------------------------------
__global__ __launch_bounds__(256) void s_kernel(const u16* __restrict__ PPh,
                                                const u16* __restrict__ PPl,
                                                float* __restrict__ S) {
    __shared__ float p1s[64][64];
    __shared__ float p2s[64][64];
    const int bn = blockIdx.x;
    const int b = bn >> 3, n = bn & 7;
    const int v0 = blockIdx.y * 256;
    const int t = threadIdx.x;
    const int tj = t >> 4, tk = t & 15;
    const int lr = t >> 4, lc = (t & 15) * 4;
    const size_t p1o = (size_t)(b * 2048) * 512 + n * 64;
    const size_t p2o = (size_t)(4096 + b * 2048) * 512 + n * 64;
    float acc[4][4] = {};

    for (int sub = 0; sub < 256; sub += 64) {
        #pragma unroll
        for (int i = 0; i < 4; i++) {
            int v = v0 + sub + lr + i * 16;
            size_t o1 = p1o + (size_t)v * 512 + lc;
            size_t o2 = p2o + (size_t)v * 512 + lc;
            ushort4 h4 = *(const ushort4*)&PPh[o1];
            ushort4 l4 = *(const ushort4*)&PPl[o1];
            p1s[lr + i * 16][lc + 0] = b2f(h4.x) + b2f(l4.x);
            p1s[lr + i * 16][lc + 1] = b2f(h4.y) + b2f(l4.y);
            p1s[lr + i * 16][lc + 2] = b2f(h4.z) + b2f(l4.z);
            p1s[lr + i * 16][lc + 3] = b2f(h4.w) + b2f(l4.w);
            h4 = *(const ushort4*)&PPh[o2];
            l4 = *(const ushort4*)&PPl[o2];
            p2s[lr + i * 16][lc + 0] = b2f(h4.x) + b2f(l4.x);
            p2s[lr + i * 16][lc + 1] = b2f(h4.y) + b2f(l4.y);
            p2s[lr + i * 16][lc + 2] = b2f(h4.z) + b2f(l4.z);
            p2s[lr + i * 16][lc + 3] = b2f(h4.w) + b2f(l4.w);
        }
        __syncthreads();
        #pragma unroll 4
        for (int v = 0; v < 64; v++) {
            float4 a4 = *(const float4*)&p2s[v][tj * 4];
            float4 b4 = *(const float4*)&p1s[v][tk * 4];
            float am[4] = {a4.x, a4.y, a4.z, a4.w};
            float bm[4] = {b4.x, b4.y, b4.z, b4.w};
            #pragma unroll
            for (int i = 0; i < 4; i++)
                #pragma unroll
                for (int j = 0; j < 4; j++)
                    acc[i][j] = fmaf(am[i], bm[j], acc[i][j]);
        }
        __syncthreads();
    }
    float* Sb = S + (size_t)bn * 64 * 64;
    #pragma unroll
    for (int i = 0; i < 4; i++)
        #pragma unroll
        for (int j = 0; j < 4; j++)
            atomicAdd(&Sb[(tj * 4 + i) * 64 + tk * 4 + j], acc[i][j]);
}

// ---------------------------------------------------------------------------
// Kernel 5: M-build, T = M@G, U^T hi/lo: UT[b][c'][(n*64+k)] = (T @ Wm_n^T)[k][c']
// grid: (16, 4 c'-chunks of 128)
// ---------------------------------------------------------------------------
__global__ __launch_bounds__(256) void tu_kernel(const float* __restrict__ S,
                                                 const float* __restrict__ halves,
                                                 const float* __restrict__ diagonals,
                                                 const float* __restrict__ Wm,
                                                 u16* __restrict__ UTh,
                                                 u16* __restrict__ UTl) {
    __shared__ float Ms[64][65];
    __shared__ float Gs[64][65];
    __shared__ float Ts[64][65];
    const int bn = blockIdx.x;
    const int b = bn >> 3, n = bn & 7;
    const int t = threadIdx.x;

    for (int idx = t; idx < 4096; idx += 256) {
        int r = idx >> 6, c = idx & 63;
        float val;
        if (r == c) {
            val = diagonals[n * 64 + r];
        } else {
            int rr = (r < c) ? r : c;
            int cc = (r < c) ? c : r;
            int h = rr * 63 - (rr * (rr - 1)) / 2 + (cc - rr - 1);
            val = halves[n * HALFN + h];
        }
        Ms[r][c] = val;
    }
    for (int idx = t; idx < 4096; idx += 256) {
        Gs[idx >> 6][idx & 63] = S[(size_t)bn * 4096 + idx];
    }
    __syncthreads();

    {   // T = M @ G
        const int tk = t >> 4, tkk = t & 15;
        float acc[4][4] = {};
        for (int j = 0; j < 64; j++) {
            float m[4], g[4];
            #pragma unroll
            for (int i = 0; i < 4; i++) m[i] = Ms[tk * 4 + i][j];
            #pragma unroll
            for (int l = 0; l < 4; l++) g[l] = Gs[j][tkk * 4 + l];
            #pragma unroll
            for (int i = 0; i < 4; i++)
                #pragma unroll
                for (int l = 0; l < 4; l++)
                    acc[i][l] = fmaf(m[i], g[l], acc[i][l]);
        }
        #pragma unroll
        for (int i = 0; i < 4; i++)
            #pragma unroll
            for (int l = 0; l < 4; l++)
                Ts[tk * 4 + i][tkk * 4 + l] = acc[i][l];
    }
    __syncthreads();

    const int c0 = blockIdx.y * 128;
    for (int iter = 0; iter < 32; iter++) {
        int flat = iter * 256 + t;      // 8192 = 128 c' x 64 k, k fastest (coalesced)
        int k = flat & 63;
        int c = c0 + (flat >> 6);
        const float* wrow = &Wm[(size_t)c * 512 + n * 64];
        float a = 0.f;
        #pragma unroll
        for (int kk = 0; kk < 64; kk += 4) {
            float4 w4 = *(const float4*)&wrow[kk];
            a = fmaf(Ts[k][kk + 0], w4.x, a);
            a = fmaf(Ts[k][kk + 1], w4.y, a);
            a = fmaf(Ts[k][kk + 2], w4.z, a);
            a = fmaf(Ts[k][kk + 3], w4.w, a);
        }
        u16 h = f2b(a), lo = f2b(a - b2f(h));
        size_t o = (size_t)b * 262144 + (size_t)c * 512 + n * 64 + k;
        UTh[o] = h; UTl[o] = lo;
    }
}

// ---------------------------------------------------------------------------
// Kernel 6: out[b] = PP1[b] @ Ucat[b] + b_mixer.  grid (4, 16, 2).
// ---------------------------------------------------------------------------
__global__ __launch_bounds__(256) void gemm_out_mfma(const u16* __restrict__ PPh,
                                                     const u16* __restrict__ PPl,
                                                     const u16* __restrict__ UTh,
                                                     const u16* __restrict__ UTl,
                                                     const float* __restrict__ bias,
                                                     float* __restrict__ out) {
    __shared__ u16 lds[16384];
    const int b = blockIdx.z;
    const u16* Ah = PPh + (size_t)b * 2048 * 512;
    const u16* Al = PPl + (size_t)b * 2048 * 512;
    const u16* Bh = UTh + (size_t)b * 512 * 512;
    const u16* Bl = UTl + (size_t)b * 512 * 512;
    f32x4 acc[4][4] = {};
    const int m0 = blockIdx.y * 128, n0 = blockIdx.x * 128;
    gemm_core(Ah, Al, Bh, Bl, m0, n0, lds, acc);
    const int t = threadIdx.x, lane = t & 63, w = t >> 6, wm = w & 1, wn = w >> 1;
    #pragma unroll
    for (int i = 0; i < 4; i++) {
        int m = m0 + wm * 64 + i * 16 + (lane >> 4) * 4;
        #pragma unroll
        for (int j = 0; j < 4; j++) {
            int n = n0 + wn * 64 + j * 16 + (lane & 15);
            float bv = bias[n];
            #pragma unroll
            for (int r = 0; r < 4; r++) {
                out[(size_t)(b * 2048 + m + r) * 512 + n] = acc[i][j][r] + bv;
            }
        }
    }
}

// ---------------------------------------------------------------------------
extern "C" void kernel_launch(void* const* d_in, const int* in_sizes, int n_in,
                              void* d_out, int out_size, void* d_ws, size_t ws_size,
                              hipStream_t stream) {
    (void)in_sizes; (void)n_in; (void)out_size; (void)ws_size;
    const float* x1        = (const float*)d_in[0];
    const float* x2        = (const float*)d_in[1];
    const float* gamma     = (const float*)d_in[2];
    const float* beta      = (const float*)d_in[3];
    const float* proj      = (const float*)d_in[4];
    const float* halves    = (const float*)d_in[5];
    const float* diagonals = (const float*)d_in[6];
    const float* Wm        = (const float*)d_in[7];
    const float* bmix      = (const float*)d_in[8];
    float* out = (float*)d_out;

    u16* us   = (u16*)d_ws;
    u16* Xh   = us;                       // 4,194,304 u16
    u16* Xl   = Xh + 4194304;
    u16* PPh  = Xl + 4194304;             // 4,194,304
    u16* PPl  = PPh + 4194304;
    u16* PwTh = PPl + 4194304;            // 262,144
    u16* PwTl = PwTh + 262144;
    u16* UTh  = PwTl + 262144;            // 524,288
    u16* UTl  = UTh + 524288;
    float* S  = (float*)(UTl + 524288);   // 65,536 f  (total ~35.3 MB)

    hipMemsetAsync(S, 0, 65536 * sizeof(float), stream);
    ln_kernel<<<dim3(8192), 256, 0, stream>>>(x1, x2, gamma, beta, Xh, Xl);
    prep_pw<<<dim3(8, 8), 256, 0, stream>>>(proj, PwTh, PwTl);
    gemm_proj_mfma<<<dim3(4, 64), 256, 0, stream>>>(Xh, Xl, PwTh, PwTl, PPh, PPl);
    s_kernel<<<dim3(16, 8), 256, 0, stream>>>(PPh, PPl, S);
    tu_kernel<<<dim3(16, 4), 256, 0, stream>>>(S, halves, diagonals, Wm, UTh, UTl);
    gemm_out_mfma<<<dim3(4, 16, 2), 256, 0, stream>>>(PPh, PPl, UTh, UTl, bmix, out);
}

// Round 3
// 162.802 us; speedup vs baseline: 1.4067x; 1.1338x over previous
//
#include <hip/hip_runtime.h>

typedef unsigned short u16;
typedef __attribute__((ext_vector_type(8))) short short8;   // 8 x bf16 (4 VGPRs)
typedef __attribute__((ext_vector_type(4))) float f32x4;

#define HALFN 2016

__device__ __forceinline__ u16 f2b(float x) {
    union { float f; unsigned u; } v; v.f = x;
    return (u16)(v.u >> 16);
}
__device__ __forceinline__ float b2f(u16 h) {
    union { float f; unsigned u; } v; v.u = ((unsigned)h) << 16;
    return v.f;
}

__device__ __forceinline__ void gll16(const void* g, void* s) {
    __builtin_amdgcn_global_load_lds(
        (const __attribute__((address_space(1))) unsigned int*)g,
        (__attribute__((address_space(3))) unsigned int*)s, 16, 0, 0);
}

// ---------------------------------------------------------------------------
// Kernel 1: LayerNorm -> bf16 hi/lo split, rows 0..4095 = x1n, 4096..8191 = x2n
// ---------------------------------------------------------------------------
__global__ __launch_bounds__(256) void ln_kernel(const float* __restrict__ x1,
                                                 const float* __restrict__ x2,
                                                 const float* __restrict__ gamma,
                                                 const float* __restrict__ beta,
                                                 u16* __restrict__ Xh,
                                                 u16* __restrict__ Xl) {
    int row = blockIdx.x;  // 0..8191
    const float* src = (row < 4096) ? (x1 + (size_t)row * 512)
                                    : (x2 + (size_t)(row - 4096) * 512);
    int t = threadIdx.x;
    float2 v = *(const float2*)&src[t * 2];
    float s  = v.x + v.y;
    float sq = v.x * v.x + v.y * v.y;
    #pragma unroll
    for (int off = 32; off > 0; off >>= 1) {
        s  += __shfl_down(s, off);
        sq += __shfl_down(sq, off);
    }
    __shared__ float ls[8], lq[8];
    int wave = t >> 6, lane = t & 63;
    if (lane == 0) { ls[wave] = s; lq[wave] = sq; }
    __syncthreads();
    if (t == 0) {
        float S = 0.f, Q = 0.f;
        #pragma unroll
        for (int i = 0; i < 4; i++) { S += ls[i]; Q += lq[i]; }
        float mu  = S * (1.0f / 512.0f);
        float var = Q * (1.0f / 512.0f) - mu * mu;
        ls[4] = mu;
        lq[4] = rsqrtf(var + 1e-5f);
    }
    __syncthreads();
    float mu = ls[4], rs = lq[4];
    float2 g  = *(const float2*)&gamma[t * 2];
    float2 bb = *(const float2*)&beta[t * 2];
    float o0 = (v.x - mu) * rs * g.x + bb.x;
    float o1 = (v.y - mu) * rs * g.y + bb.y;
    u16 h0 = f2b(o0), h1 = f2b(o1);
    u16 l0 = f2b(o0 - b2f(h0)), l1 = f2b(o1 - b2f(h1));
    ushort2 H; H.x = h0; H.y = h1;
    ushort2 L; L.x = l0; L.y = l1;
    *(ushort2*)&Xh[(size_t)row * 512 + t * 2] = H;
    *(ushort2*)&Xl[(size_t)row * 512 + t * 2] = L;
}

// ---------------------------------------------------------------------------
// Kernel 2: transpose+split proj[n][c][k] -> PwT hi/lo [(n*64+k)][c]
// ---------------------------------------------------------------------------
__global__ __launch_bounds__(256) void prep_pw(const float* __restrict__ proj,
                                               u16* __restrict__ PwTh,
                                               u16* __restrict__ PwTl) {
    __shared__ float tile[64][65];
    const int n = blockIdx.x, c0 = blockIdx.y * 64;
    const int t = threadIdx.x;
    #pragma unroll
    for (int i = 0; i < 4; i++) {
        int flat = i * 256 + t;
        int c = flat >> 4, k4 = (flat & 15) * 4;
        float4 v = *(const float4*)&proj[(size_t)n * 32768 + (size_t)(c0 + c) * 64 + k4];
        tile[c][k4 + 0] = v.x; tile[c][k4 + 1] = v.y;
        tile[c][k4 + 2] = v.z; tile[c][k4 + 3] = v.w;
    }
    __syncthreads();
    #pragma unroll
    for (int i = 0; i < 16; i++) {
        int flat = i * 256 + t;
        int k = flat >> 6, c = flat & 63;
        float v = tile[c][k];
        u16 h = f2b(v), lo = f2b(v - b2f(h));
        size_t o = (size_t)(n * 64 + k) * 512 + c0 + c;
        PwTh[o] = h; PwTl[o] = lo;
    }
}

// ---------------------------------------------------------------------------
// MFMA bf16x3 GEMM core, TM x TN tile, BK=32, K=512, ld=512.
// XOR-swizzled LDS (global_load_lds staging, conflict-free frag reads).
// ---------------------------------------------------------------------------
template<int TM, int TN>
__device__ __forceinline__ void gemm_core(const u16* __restrict__ Ah,
                                          const u16* __restrict__ Al,
                                          const u16* __restrict__ Bh,
                                          const u16* __restrict__ Bl,
                                          int m0, int n0, u16* lds,
                                          f32x4 (&acc)[TM / 32][TN / 32]) {
    constexpr int MI = TM / 32, NI = TN / 32;
    constexpr int LA = TM * 32, LB = TN * 32;
    const int t = threadIdx.x;
    const int lane = t & 63;
    const int w = t >> 6, wm = w & 1, wn = w >> 1;
    const int fr = lane & 15, q = lane >> 4;

    int aoff[MI], boff[NI];
    #pragma unroll
    for (int i = 0; i < MI; i++) {
        int r = wm * (TM / 2) + i * 16 + fr;
        aoff[i] = r * 32 + ((q ^ ((r >> 1) & 3)) * 8);
    }
    #pragma unroll
    for (int j = 0; j < NI; j++) {
        int r = wn * (TN / 2) + j * 16 + fr;
        boff[j] = r * 32 + ((q ^ ((r >> 1) & 3)) * 8);
    }

    for (int kt = 0; kt < 512; kt += 32) {
        #pragma unroll
        for (int p = 0; p < TM / 64; p++) {
            int o = p * 4096 + t * 16;
            int r = o >> 6;
            int kc = ((o >> 4) & 3) ^ ((r >> 1) & 3);
            size_t g = (size_t)(m0 + r) * 512 + kt + kc * 8;
            int le = o >> 1;
            gll16(Ah + g, lds + le);
            gll16(Al + g, lds + LA + le);
        }
        #pragma unroll
        for (int p = 0; p < TN / 64; p++) {
            int o = p * 4096 + t * 16;
            int r = o >> 6;
            int kc = ((o >> 4) & 3) ^ ((r >> 1) & 3);
            size_t g = (size_t)(n0 + r) * 512 + kt + kc * 8;
            int le = o >> 1;
            gll16(Bh + g, lds + 2 * LA + le);
            gll16(Bl + g, lds + 2 * LA + LB + le);
        }
        __syncthreads();
        short8 afh[MI], afl[MI], bfh[NI], bfl[NI];
        #pragma unroll
        for (int i = 0; i < MI; i++) {
            afh[i] = *(const short8*)(lds + aoff[i]);
            afl[i] = *(const short8*)(lds + LA + aoff[i]);
        }
        #pragma unroll
        for (int j = 0; j < NI; j++) {
            bfh[j] = *(const short8*)(lds + 2 * LA + boff[j]);
            bfl[j] = *(const short8*)(lds + 2 * LA + LB + boff[j]);
        }
        #pragma unroll
        for (int i = 0; i < MI; i++)
            #pragma unroll
            for (int j = 0; j < NI; j++) {
                acc[i][j] = __builtin_amdgcn_mfma_f32_16x16x32_bf16(afh[i], bfh[j], acc[i][j], 0, 0, 0);
                acc[i][j] = __builtin_amdgcn_mfma_f32_16x16x32_bf16(afh[i], bfl[j], acc[i][j], 0, 0, 0);
                acc[i][j] = __builtin_amdgcn_mfma_f32_16x16x32_bf16(afl[i], bfh[j], acc[i][j], 0, 0, 0);
            }
        __syncthreads();
    }
}

// ---------------------------------------------------------------------------
// Kernel 3: PP = Xn @ Pw, 128x64 tile, grid (8 n-tiles, 64 m-tiles) = 512.
// ---------------------------------------------------------------------------
__global__ __launch_bounds__(256) void gemm_proj_mfma(const u16* __restrict__ Xh,
                                                      const u16* __restrict__ Xl,
                                                      const u16* __restrict__ PwTh,
                                                      const u16* __restrict__ PwTl,
                                                      u16* __restrict__ PPh,
                                                      u16* __restrict__ PPl) {
    __shared__ u16 lds[12288];   // 2*128*32 + 2*64*32
    f32x4 acc[4][2] = {};
    const int m0 = blockIdx.y * 128, n0 = blockIdx.x * 64;
    gemm_core<128, 64>(Xh, Xl, PwTh, PwTl, m0, n0, lds, acc);
    const int t = threadIdx.x, lane = t & 63, w = t >> 6, wm = w & 1, wn = w >> 1;
    const int fr = lane & 15, q = lane >> 4;
    #pragma unroll
    for (int i = 0; i < 4; i++) {
        int m = m0 + wm * 64 + i * 16 + q * 4;
        #pragma unroll
        for (int j = 0; j < 2; j++) {
            int n = n0 + wn * 32 + j * 16 + fr;
            #pragma unroll
            for (int r = 0; r < 4; r++) {
                float v = acc[i][j][r];
                u16 h = f2b(v);
                u16 l = f2b(v - b2f(h));
                size_t o = (size_t)(m + r) * 512 + n;
                PPh[o] = h; PPl[o] = l;
            }
        }
    }
}

// ---------------------------------------------------------------------------
// Kernel 4 (MFMA): G[b,n] = P2^T P1 per (b,n).  grid (16 bn, 8 v-chunks).
// Register 4x4 transpose -> XOR-swizzled LDS -> bf16x3 MFMA, atomic reduce.
// ---------------------------------------------------------------------------
__global__ __launch_bounds__(256) void s_kernel(const u16* __restrict__ PPh,
                                                const u16* __restrict__ PPl,
                                                float* __restrict__ S) {
    __shared__ u16 lds[4][4096];   // [p2h,p2l,p1h,p1l][row(j/kk) * 64 + v-swizzled]
    const int bn = blockIdx.x, b = bn >> 3, n = bn & 7;
    const int vc = blockIdx.y;
    const int t = threadIdx.x, lane = t & 63, w = t >> 6;
    const int jg = t & 15, vg = t >> 4;
    const int fr = lane & 15, q = lane >> 4;
    const size_t p1o = (size_t)(b * 2048) * 512 + n * 64;
    const size_t p2o = (size_t)(4096 + b * 2048) * 512 + n * 64;
    f32x4 acc[4] = {};

    // frag read offsets (precomputed): row r, chunk (kc*4+q)^s(r)
    int arow = w * 16 + fr;
    int sa = ((arow >> 2) & 7) ^ ((arow & 3) << 1);
    int aofs[2];
    #pragma unroll
    for (int kc = 0; kc < 2; kc++)
        aofs[kc] = arow * 64 + (((kc * 4 + q) ^ sa) & 7) * 8;
    int bofs[4][2];
    #pragma unroll
    for (int j16 = 0; j16 < 4; j16++) {
        int brow = j16 * 16 + fr;
        int sb = ((brow >> 2) & 7) ^ ((brow & 3) << 1);
        #pragma unroll
        for (int kc = 0; kc < 2; kc++)
            bofs[j16][kc] = brow * 64 + (((kc * 4 + q) ^ sb) & 7) * 8;
    }

    for (int sub = 0; sub < 4; sub++) {
        int vb = vc * 256 + sub * 64;
        // load 4 rows x 4 cols per array, transpose in regs, swizzled ds_write_b64
        ushort4 L[4][4];   // [array][v-row]
        #pragma unroll
        for (int r = 0; r < 4; r++) {
            size_t o2 = p2o + (size_t)(vb + vg * 4 + r) * 512 + jg * 4;
            size_t o1 = p1o + (size_t)(vb + vg * 4 + r) * 512 + jg * 4;
            L[0][r] = *(const ushort4*)&PPh[o2];
            L[1][r] = *(const ushort4*)&PPl[o2];
            L[2][r] = *(const ushort4*)&PPh[o1];
            L[3][r] = *(const ushort4*)&PPl[o1];
        }
        __syncthreads();   // protect LDS from previous iteration's reads
        #pragma unroll
        for (int a = 0; a < 4; a++) {
            #pragma unroll
            for (int c = 0; c < 4; c++) {
                ushort4 tv;
                tv.x = ((const u16*)&L[a][0])[c];
                tv.y = ((const u16*)&L[a][1])[c];
                tv.z = ((const u16*)&L[a][2])[c];
                tv.w = ((const u16*)&L[a][3])[c];
                int row = jg * 4 + c;
                int s = ((row >> 2) & 7) ^ ((row & 3) << 1);
                int v4 = (vg * 4) ^ ((s & 7) * 8);
                *(ushort4*)&lds[a][row * 64 + v4] = tv;
            }
        }
        __syncthreads();
        #pragma unroll
        for (int kc = 0; kc < 2; kc++) {
            short8 ah = *(const short8*)&lds[0][aofs[kc]];
            short8 al = *(const short8*)&lds[1][aofs[kc]];
            #pragma unroll
            for (int j16 = 0; j16 < 4; j16++) {
                short8 bh = *(const short8*)&lds[2][bofs[j16][kc]];
                short8 bl = *(const short8*)&lds[3][bofs[j16][kc]];
                acc[j16] = __builtin_amdgcn_mfma_f32_16x16x32_bf16(ah, bh, acc[j16], 0, 0, 0);
                acc[j16] = __builtin_amdgcn_mfma_f32_16x16x32_bf16(ah, bl, acc[j16], 0, 0, 0);
                acc[j16] = __builtin_amdgcn_mfma_f32_16x16x32_bf16(al, bh, acc[j16], 0, 0, 0);
            }
        }
    }
    // C[j][kk]: j = w*16 + q*4 + r, kk = j16*16 + fr
    float* Sb = S + (size_t)bn * 4096;
    #pragma unroll
    for (int j16 = 0; j16 < 4; j16++)
        #pragma unroll
        for (int r = 0; r < 4; r++)
            atomicAdd(&Sb[(w * 16 + q * 4 + r) * 64 + j16 * 16 + fr], acc[j16][r]);
}

// ---------------------------------------------------------------------------
// Kernel 5a: build metric M_n, T_bn = M @ G.  grid (16 bn, 4 l-chunks of 16).
// ---------------------------------------------------------------------------
__global__ __launch_bounds__(256) void tu_a(const float* __restrict__ S,
                                            const float* __restrict__ halves,
                                            const float* __restrict__ diagonals,
                                            float* __restrict__ Tbuf) {
    __shared__ float Ms[64][65];
    __shared__ float Gs[64][68];
    const int bn = blockIdx.x;
    const int n = bn & 7;
    const int t = threadIdx.x;

    for (int idx = t; idx < 4096; idx += 256) {
        int r = idx >> 6, c = idx & 63;
        float val;
        if (r == c) {
            val = diagonals[n * 64 + r];
        } else {
            int rr = (r < c) ? r : c;
            int cc = (r < c) ? c : r;
            int h = rr * 63 - (rr * (rr - 1)) / 2 + (cc - rr - 1);
            val = halves[n * HALFN + h];
        }
        Ms[r][c] = val;
    }
    for (int idx = t; idx < 4096; idx += 256) {
        Gs[idx >> 6][idx & 63] = S[(size_t)bn * 4096 + idx];
    }
    __syncthreads();

    const int k = t & 63, lq = t >> 6;
    const int l = blockIdx.y * 16 + lq * 4;
    float4 a = {0.f, 0.f, 0.f, 0.f};
    #pragma unroll 8
    for (int j = 0; j < 64; j++) {
        float m = Ms[k][j];
        float4 g = *(const float4*)&Gs[j][l];
        a.x = fmaf(m, g.x, a.x);
        a.y = fmaf(m, g.y, a.y);
        a.z = fmaf(m, g.z, a.z);
        a.w = fmaf(m, g.w, a.w);
    }
    *(float4*)&Tbuf[(size_t)bn * 4096 + k * 64 + l] = a;
}

// ---------------------------------------------------------------------------
// Kernel 5b: UT[b][c'][(n,k)] = sum_kk T_bn[k][kk] * Wm[c'][n*64+kk], hi/lo.
// grid (16 bn, 8 c-chunks of 64).  T register-chunked, Wm wave-uniform loads.
// ---------------------------------------------------------------------------
__global__ __launch_bounds__(256) void tu_b(const float* __restrict__ Tbuf,
                                            const float* __restrict__ Wm,
                                            u16* __restrict__ UTh,
                                            u16* __restrict__ UTl) {
    __shared__ float Ts[64][68];   // chunk-of-16 position XOR-swizzled by (k&3)
    const int bn = blockIdx.x, b = bn >> 3, n = bn & 7;
    const int t = threadIdx.x;
    #pragma unroll
    for (int i = 0; i < 4; i++) {
        int flat4 = i * 256 + t;            // 1024 float4
        int kk = flat4 >> 4, kk4 = (flat4 & 15) * 4;
        float4 v = *(const float4*)&Tbuf[(size_t)bn * 4096 + kk * 64 + kk4];
        int pos = (((kk4 >> 4) ^ (kk & 3)) * 16) + (kk4 & 15);
        *(float4*)&Ts[kk][pos] = v;
    }
    __syncthreads();

    const int k = t & 63, cg = t >> 6;
    const int c0 = blockIdx.y * 64 + cg * 16;
    float acc[16] = {};
    #pragma unroll
    for (int kkc = 0; kkc < 4; kkc++) {
        const float* tp = &Ts[k][(kkc ^ (k & 3)) * 16];
        float ts[16];
        #pragma unroll
        for (int u = 0; u < 4; u++) {
            float4 t4 = *(const float4*)&tp[u * 4];
            ts[u * 4 + 0] = t4.x; ts[u * 4 + 1] = t4.y;
            ts[u * 4 + 2] = t4.z; ts[u * 4 + 3] = t4.w;
        }
        #pragma unroll
        for (int i = 0; i < 16; i++) {
            const float* wrow = &Wm[(size_t)(c0 + i) * 512 + n * 64 + kkc * 16];
            #pragma unroll
            for (int u = 0; u < 4; u++) {
                float4 w4 = *(const float4*)&wrow[u * 4];
                acc[i] = fmaf(ts[u * 4 + 0], w4.x, acc[i]);
                acc[i] = fmaf(ts[u * 4 + 1], w4.y, acc[i]);
                acc[i] = fmaf(ts[u * 4 + 2], w4.z, acc[i]);
                acc[i] = fmaf(ts[u * 4 + 3], w4.w, acc[i]);
            }
        }
    }
    #pragma unroll
    for (int i = 0; i < 16; i++) {
        u16 h = f2b(acc[i]), lo = f2b(acc[i] - b2f(h));
        size_t o = (size_t)b * 262144 + (size_t)(c0 + i) * 512 + n * 64 + k;
        UTh[o] = h; UTl[o] = lo;
    }
}

// ---------------------------------------------------------------------------
// Kernel 6: out[b] = PP1[b] @ Ucat[b] + b_mixer.  64x64 tile, grid (8,32,2).
// ---------------------------------------------------------------------------
__global__ __launch_bounds__(256) void gemm_out_mfma(const u16* __restrict__ PPh,
                                                     const u16* __restrict__ PPl,
                                                     const u16* __restrict__ UTh,
                                                     const u16* __restrict__ UTl,
                                                     const float* __restrict__ bias,
                                                     float* __restrict__ out) {
    __shared__ u16 lds[8192];   // 2*64*32 + 2*64*32
    const int b = blockIdx.z;
    const u16* Ah = PPh + (size_t)b * 2048 * 512;
    const u16* Al = PPl + (size_t)b * 2048 * 512;
    const u16* Bh = UTh + (size_t)b * 512 * 512;
    const u16* Bl = UTl + (size_t)b * 512 * 512;
    f32x4 acc[2][2] = {};
    const int m0 = blockIdx.y * 64, n0 = blockIdx.x * 64;
    gemm_core<64, 64>(Ah, Al, Bh, Bl, m0, n0, lds, acc);
    const int t = threadIdx.x, lane = t & 63, w = t >> 6, wm = w & 1, wn = w >> 1;
    const int fr = lane & 15, q = lane >> 4;
    #pragma unroll
    for (int i = 0; i < 2; i++) {
        int m = m0 + wm * 32 + i * 16 + q * 4;
        #pragma unroll
        for (int j = 0; j < 2; j++) {
            int n = n0 + wn * 32 + j * 16 + fr;
            float bv = bias[n];
            #pragma unroll
            for (int r = 0; r < 4; r++) {
                out[(size_t)(b * 2048 + m + r) * 512 + n] = acc[i][j][r] + bv;
            }
        }
    }
}

// ---------------------------------------------------------------------------
extern "C" void kernel_launch(void* const* d_in, const int* in_sizes, int n_in,
                              void* d_out, int out_size, void* d_ws, size_t ws_size,
                              hipStream_t stream) {
    (void)in_sizes; (void)n_in; (void)out_size; (void)ws_size;
    const float* x1        = (const float*)d_in[0];
    const float* x2        = (const float*)d_in[1];
    const float* gamma     = (const float*)d_in[2];
    const float* beta      = (const float*)d_in[3];
    const float* proj      = (const float*)d_in[4];
    const float* halves    = (const float*)d_in[5];
    const float* diagonals = (const float*)d_in[6];
    const float* Wm        = (const float*)d_in[7];
    const float* bmix      = (const float*)d_in[8];
    float* out = (float*)d_out;

    u16* us   = (u16*)d_ws;
    u16* Xh   = us;                       // 4,194,304 u16 each
    u16* Xl   = Xh + 4194304;
    u16* PPh  = Xl + 4194304;
    u16* PPl  = PPh + 4194304;
    u16* PwTh = PPl + 4194304;            // 262,144
    u16* PwTl = PwTh + 262144;
    u16* UTh  = PwTl + 262144;            // 524,288
    u16* UTl  = UTh + 524288;
    float* S    = (float*)(UTl + 524288); // 65,536 f
    float* Tbuf = S + 65536;              // 65,536 f

    hipMemsetAsync(S, 0, 65536 * sizeof(float), stream);
    ln_kernel<<<dim3(8192), 256, 0, stream>>>(x1, x2, gamma, beta, Xh, Xl);
    prep_pw<<<dim3(8, 8), 256, 0, stream>>>(proj, PwTh, PwTl);
    gemm_proj_mfma<<<dim3(8, 64), 256, 0, stream>>>(Xh, Xl, PwTh, PwTl, PPh, PPl);
    s_kernel<<<dim3(16, 8), 256, 0, stream>>>(PPh, PPl, S);
    tu_a<<<dim3(16, 4), 256, 0, stream>>>(S, halves, diagonals, Tbuf);
    tu_b<<<dim3(16, 8), 256, 0, stream>>>(Tbuf, Wm, UTh, UTl);
    gemm_out_mfma<<<dim3(8, 32, 2), 256, 0, stream>>>(PPh, PPl, UTh, UTl, bmix, out);
}

// Round 4
// 147.039 us; speedup vs baseline: 1.5575x; 1.1072x over previous
//
#include <hip/hip_runtime.h>

typedef unsigned short u16;
typedef __attribute__((ext_vector_type(8))) short short8;   // 8 x bf16 (4 VGPRs)
typedef __attribute__((ext_vector_type(4))) float f32x4;

#define HALFN 2016

__device__ __forceinline__ u16 f2b(float x) {            // truncate
    union { float f; unsigned u; } v; v.f = x;
    return (u16)(v.u >> 16);
}
__device__ __forceinline__ u16 f2b_rn(float x) {         // round-nearest-even
    union { float f; unsigned u; } v; v.f = x;
    unsigned r = v.u + 0x7FFFu + ((v.u >> 16) & 1u);
    return (u16)(r >> 16);
}
__device__ __forceinline__ float b2f(u16 h) {
    union { float f; unsigned u; } v; v.u = ((unsigned)h) << 16;
    return v.f;
}

__device__ __forceinline__ void gll16(const void* g, void* s) {
    __builtin_amdgcn_global_load_lds(
        (const __attribute__((address_space(1))) unsigned int*)g,
        (__attribute__((address_space(3))) unsigned int*)s, 16, 0, 0);
}

// ---------------------------------------------------------------------------
// Kernel 1 (fused): blocks 0..8191 LayerNorm -> Xh (RN bf16);
// blocks 8192..8255 prep Pw (transpose+split); block 8256 zeroes S.
// ---------------------------------------------------------------------------
__global__ __launch_bounds__(256) void ln_prep(const float* __restrict__ x1,
                                               const float* __restrict__ x2,
                                               const float* __restrict__ gamma,
                                               const float* __restrict__ beta,
                                               const float* __restrict__ proj,
                                               u16* __restrict__ Xh,
                                               u16* __restrict__ Pwh,
                                               u16* __restrict__ Pwl,
                                               float* __restrict__ S) {
    __shared__ float ls[8], lq[8];
    __shared__ float tile[64][65];
    const int bid = blockIdx.x, t = threadIdx.x;

    if (bid < 8192) {
        const float* src = (bid < 4096) ? (x1 + (size_t)bid * 512)
                                        : (x2 + (size_t)(bid - 4096) * 512);
        float2 v = *(const float2*)&src[t * 2];
        float s  = v.x + v.y;
        float sq = v.x * v.x + v.y * v.y;
        #pragma unroll
        for (int off = 32; off > 0; off >>= 1) {
            s  += __shfl_down(s, off);
            sq += __shfl_down(sq, off);
        }
        int wave = t >> 6, lane = t & 63;
        if (lane == 0) { ls[wave] = s; lq[wave] = sq; }
        __syncthreads();
        if (t == 0) {
            float Sm = 0.f, Q = 0.f;
            #pragma unroll
            for (int i = 0; i < 4; i++) { Sm += ls[i]; Q += lq[i]; }
            float mu  = Sm * (1.0f / 512.0f);
            float var = Q * (1.0f / 512.0f) - mu * mu;
            ls[4] = mu;
            lq[4] = rsqrtf(var + 1e-5f);
        }
        __syncthreads();
        float mu = ls[4], rs = lq[4];
        float2 g  = *(const float2*)&gamma[t * 2];
        float2 bb = *(const float2*)&beta[t * 2];
        float o0 = (v.x - mu) * rs * g.x + bb.x;
        float o1 = (v.y - mu) * rs * g.y + bb.y;
        ushort2 H; H.x = f2b_rn(o0); H.y = f2b_rn(o1);
        *(ushort2*)&Xh[(size_t)bid * 512 + t * 2] = H;
    } else if (bid < 8256) {
        const int id = bid - 8192;
        const int n = id >> 3, c0 = (id & 7) * 64;
        #pragma unroll
        for (int i = 0; i < 4; i++) {
            int flat = i * 256 + t;
            int c = flat >> 4, k4 = (flat & 15) * 4;
            float4 v = *(const float4*)&proj[(size_t)n * 32768 + (size_t)(c0 + c) * 64 + k4];
            tile[c][k4 + 0] = v.x; tile[c][k4 + 1] = v.y;
            tile[c][k4 + 2] = v.z; tile[c][k4 + 3] = v.w;
        }
        __syncthreads();
        #pragma unroll
        for (int i = 0; i < 16; i++) {
            int flat = i * 256 + t;
            int k = flat >> 6, c = flat & 63;
            float v = tile[c][k];
            u16 h = f2b(v), lo = f2b(v - b2f(h));
            size_t o = (size_t)(n * 64 + k) * 512 + c0 + c;
            Pwh[o] = h; Pwl[o] = lo;
        }
    } else {
        float4 z = {0.f, 0.f, 0.f, 0.f};
        #pragma unroll
        for (int i = 0; i < 64; i++)
            *(float4*)&S[(size_t)(i * 256 + t) * 4] = z;
    }
}

// ---------------------------------------------------------------------------
// MFMA bf16x2 GEMM core: A single buffer (hi RN), B hi/lo pair.  TMxTN tile,
// BK=32, K=512, ld=512.  XOR-swizzled LDS, gll16 staging.
// ---------------------------------------------------------------------------
template<int TM, int TN>
__device__ __forceinline__ void gemm_core_a1b2(const u16* __restrict__ A,
                                               const u16* __restrict__ Bh,
                                               const u16* __restrict__ Bl,
                                               int m0, int n0, u16* lds,
                                               f32x4 (&acc)[TM / 32][TN / 32]) {
    constexpr int MI = TM / 32, NI = TN / 32;
    constexpr int LA = TM * 32, LB = TN * 32;
    const int t = threadIdx.x;
    const int lane = t & 63;
    const int w = t >> 6, wm = w & 1, wn = w >> 1;
    const int fr = lane & 15, q = lane >> 4;

    int aoff[MI], boff[NI];
    #pragma unroll
    for (int i = 0; i < MI; i++) {
        int r = wm * (TM / 2) + i * 16 + fr;
        aoff[i] = r * 32 + ((q ^ ((r >> 1) & 3)) * 8);
    }
    #pragma unroll
    for (int j = 0; j < NI; j++) {
        int r = wn * (TN / 2) + j * 16 + fr;
        boff[j] = r * 32 + ((q ^ ((r >> 1) & 3)) * 8);
    }

    for (int kt = 0; kt < 512; kt += 32) {
        #pragma unroll
        for (int p = 0; p < TM / 64; p++) {
            int o = p * 4096 + t * 16;
            int r = o >> 6;
            int kc = ((o >> 4) & 3) ^ ((r >> 1) & 3);
            size_t g = (size_t)(m0 + r) * 512 + kt + kc * 8;
            gll16(A + g, lds + (o >> 1));
        }
        #pragma unroll
        for (int p = 0; p < TN / 64; p++) {
            int o = p * 4096 + t * 16;
            int r = o >> 6;
            int kc = ((o >> 4) & 3) ^ ((r >> 1) & 3);
            size_t g = (size_t)(n0 + r) * 512 + kt + kc * 8;
            gll16(Bh + g, lds + LA + (o >> 1));
            gll16(Bl + g, lds + LA + LB + (o >> 1));
        }
        __syncthreads();
        short8 af[MI], bfh[NI], bfl[NI];
        #pragma unroll
        for (int i = 0; i < MI; i++)
            af[i] = *(const short8*)(lds + aoff[i]);
        #pragma unroll
        for (int j = 0; j < NI; j++) {
            bfh[j] = *(const short8*)(lds + LA + boff[j]);
            bfl[j] = *(const short8*)(lds + LA + LB + boff[j]);
        }
        #pragma unroll
        for (int i = 0; i < MI; i++)
            #pragma unroll
            for (int j = 0; j < NI; j++) {
                acc[i][j] = __builtin_amdgcn_mfma_f32_16x16x32_bf16(af[i], bfh[j], acc[i][j], 0, 0, 0);
                acc[i][j] = __builtin_amdgcn_mfma_f32_16x16x32_bf16(af[i], bfl[j], acc[i][j], 0, 0, 0);
            }
        __syncthreads();
    }
}

// ---------------------------------------------------------------------------
// Kernel 2: PP = Xn @ Pw (128x64 tiles, grid (8,64)=512 blocks).
// x1-half epilogue: PPh natural (RN) + PPT1h transposed (RN).
// x2-half epilogue: PPT2h transposed (RN) only.
// PPT layout: [b][c(512)][v(2048)].
// ---------------------------------------------------------------------------
__global__ __launch_bounds__(256) void gemm_proj_mfma(const u16* __restrict__ Xh,
                                                      const u16* __restrict__ Pwh,
                                                      const u16* __restrict__ Pwl,
                                                      u16* __restrict__ PPh,
                                                      u16* __restrict__ PPT1h,
                                                      u16* __restrict__ PPT2h) {
    __shared__ u16 lds[8192];   // 128*32 + 2*64*32
    f32x4 acc[4][2] = {};
    const int m0 = blockIdx.y * 128, n0 = blockIdx.x * 64;
    gemm_core_a1b2<128, 64>(Xh, Pwh, Pwl, m0, n0, lds, acc);
    const int t = threadIdx.x, lane = t & 63, w = t >> 6, wm = w & 1, wn = w >> 1;
    const int fr = lane & 15, q = lane >> 4;
    const int src2 = (m0 >= 4096);
    const int b = (m0 & 4095) >> 11;
    const int v00 = m0 & 2047;
    #pragma unroll
    for (int i = 0; i < 4; i++) {
        int mloc = wm * 64 + i * 16 + q * 4;
        int v = v00 + mloc;
        #pragma unroll
        for (int j = 0; j < 2; j++) {
            int n = n0 + wn * 32 + j * 16 + fr;
            u16 hs[4];
            #pragma unroll
            for (int r = 0; r < 4; r++) hs[r] = f2b_rn(acc[i][j][r]);
            ushort4 hv; hv.x = hs[0]; hv.y = hs[1]; hv.z = hs[2]; hv.w = hs[3];
            if (!src2) {
                #pragma unroll
                for (int r = 0; r < 4; r++)
                    PPh[(size_t)(m0 + mloc + r) * 512 + n] = hs[r];
                *(ushort4*)&PPT1h[((size_t)(b * 512 + n)) * 2048 + v] = hv;
            } else {
                *(ushort4*)&PPT2h[((size_t)(b * 512 + n)) * 2048 + v] = hv;
            }
        }
    }
}

// ---------------------------------------------------------------------------
// Kernel 3: G[b,n] = P2^T P1 via single-product MFMA over K=v.
// grid (16 bn, 8 v-splits of 256).  A=PPT2h rows j, B=PPT1h rows kk, ld=2048.
// ---------------------------------------------------------------------------
__global__ __launch_bounds__(256) void s_kernel(const u16* __restrict__ PPT2h,
                                                const u16* __restrict__ PPT1h,
                                                float* __restrict__ S) {
    __shared__ u16 lds[4096];   // A 64x32 + B 64x32
    const int bn = blockIdx.x, b = bn >> 3, n = bn & 7;
    const u16* A = PPT2h + ((size_t)(b * 512 + n * 64)) * 2048;
    const u16* B = PPT1h + ((size_t)(b * 512 + n * 64)) * 2048;
    const int t = threadIdx.x, lane = t & 63, w = t >> 6, wm = w & 1, wn = w >> 1;
    const int fr = lane & 15, q = lane >> 4;

    int aoff[2], boff[2];
    #pragma unroll
    for (int i = 0; i < 2; i++) {
        int r = wm * 32 + i * 16 + fr;
        aoff[i] = r * 32 + ((q ^ ((r >> 1) & 3)) * 8);
    }
    #pragma unroll
    for (int j = 0; j < 2; j++) {
        int r = wn * 32 + j * 16 + fr;
        boff[j] = r * 32 + ((q ^ ((r >> 1) & 3)) * 8);
    }
    const int o = t * 16;
    const int rr = o >> 6;
    const int kc = ((o >> 4) & 3) ^ ((rr >> 1) & 3);
    const int le = o >> 1;

    f32x4 acc[2][2] = {};
    const int k0 = blockIdx.y * 256;
    for (int kt = k0; kt < k0 + 256; kt += 32) {
        size_t g = (size_t)rr * 2048 + kt + kc * 8;
        gll16(A + g, lds + le);
        gll16(B + g, lds + 2048 + le);
        __syncthreads();
        short8 af[2], bf[2];
        #pragma unroll
        for (int i = 0; i < 2; i++) af[i] = *(const short8*)(lds + aoff[i]);
        #pragma unroll
        for (int j = 0; j < 2; j++) bf[j] = *(const short8*)(lds + 2048 + boff[j]);
        #pragma unroll
        for (int i = 0; i < 2; i++)
            #pragma unroll
            for (int j = 0; j < 2; j++)
                acc[i][j] = __builtin_amdgcn_mfma_f32_16x16x32_bf16(af[i], bf[j], acc[i][j], 0, 0, 0);
        __syncthreads();
    }
    float* Sb = S + (size_t)bn * 4096;
    #pragma unroll
    for (int i = 0; i < 2; i++) {
        int jrow = wm * 32 + i * 16 + q * 4;
        #pragma unroll
        for (int j = 0; j < 2; j++) {
            int kk = wn * 32 + j * 16 + fr;
            #pragma unroll
            for (int r = 0; r < 4; r++)
                atomicAdd(&Sb[(jrow + r) * 64 + kk], acc[i][j][r]);
        }
    }
}

// ---------------------------------------------------------------------------
// Kernel 4a: build metric M_n, T_bn = M @ G.  grid (16 bn, 4 l-chunks of 16).
// ---------------------------------------------------------------------------
__global__ __launch_bounds__(256) void tu_a(const float* __restrict__ S,
                                            const float* __restrict__ halves,
                                            const float* __restrict__ diagonals,
                                            float* __restrict__ Tbuf) {
    __shared__ float Ms[64][65];
    __shared__ float Gs[64][68];
    const int bn = blockIdx.x;
    const int n = bn & 7;
    const int t = threadIdx.x;

    for (int idx = t; idx < 4096; idx += 256) {
        int r = idx >> 6, c = idx & 63;
        float val;
        if (r == c) {
            val = diagonals[n * 64 + r];
        } else {
            int rr = (r < c) ? r : c;
            int cc = (r < c) ? c : r;
            int h = rr * 63 - (rr * (rr - 1)) / 2 + (cc - rr - 1);
            val = halves[n * HALFN + h];
        }
        Ms[r][c] = val;
    }
    for (int idx = t; idx < 4096; idx += 256) {
        Gs[idx >> 6][idx & 63] = S[(size_t)bn * 4096 + idx];
    }
    __syncthreads();

    const int k = t & 63, lq = t >> 6;
    const int l = blockIdx.y * 16 + lq * 4;
    float4 a = {0.f, 0.f, 0.f, 0.f};
    #pragma unroll 8
    for (int j = 0; j < 64; j++) {
        float m = Ms[k][j];
        float4 g = *(const float4*)&Gs[j][l];
        a.x = fmaf(m, g.x, a.x);
        a.y = fmaf(m, g.y, a.y);
        a.z = fmaf(m, g.z, a.z);
        a.w = fmaf(m, g.w, a.w);
    }
    *(float4*)&Tbuf[(size_t)bn * 4096 + k * 64 + l] = a;
}

// ---------------------------------------------------------------------------
// Kernel 4b: UT[b][c'][(n,k)] = sum_kk T_bn[k][kk] * Wm[c'][n*64+kk], hi/lo.
// grid (16 bn, 8 c-chunks of 64).
// ---------------------------------------------------------------------------
__global__ __launch_bounds__(256) void tu_b(const float* __restrict__ Tbuf,
                                            const float* __restrict__ Wm,
                                            u16* __restrict__ UTh,
                                            u16* __restrict__ UTl) {
    __shared__ float Ts[64][68];
    const int bn = blockIdx.x, b = bn >> 3, n = bn & 7;
    const int t = threadIdx.x;
    #pragma unroll
    for (int i = 0; i < 4; i++) {
        int flat4 = i * 256 + t;
        int kk = flat4 >> 4, kk4 = (flat4 & 15) * 4;
        float4 v = *(const float4*)&Tbuf[(size_t)bn * 4096 + kk * 64 + kk4];
        int pos = (((kk4 >> 4) ^ (kk & 3)) * 16) + (kk4 & 15);
        *(float4*)&Ts[kk][pos] = v;
    }
    __syncthreads();

    const int k = t & 63, cg = t >> 6;
    const int c0 = blockIdx.y * 64 + cg * 16;
    float acc[16] = {};
    #pragma unroll
    for (int kkc = 0; kkc < 4; kkc++) {
        const float* tp = &Ts[k][(kkc ^ (k & 3)) * 16];
        float ts[16];
        #pragma unroll
        for (int u = 0; u < 4; u++) {
            float4 t4 = *(const float4*)&tp[u * 4];
            ts[u * 4 + 0] = t4.x; ts[u * 4 + 1] = t4.y;
            ts[u * 4 + 2] = t4.z; ts[u * 4 + 3] = t4.w;
        }
        #pragma unroll
        for (int i = 0; i < 16; i++) {
            const float* wrow = &Wm[(size_t)(c0 + i) * 512 + n * 64 + kkc * 16];
            #pragma unroll
            for (int u = 0; u < 4; u++) {
                float4 w4 = *(const float4*)&wrow[u * 4];
                acc[i] = fmaf(ts[u * 4 + 0], w4.x, acc[i]);
                acc[i] = fmaf(ts[u * 4 + 1], w4.y, acc[i]);
                acc[i] = fmaf(ts[u * 4 + 2], w4.z, acc[i]);
                acc[i] = fmaf(ts[u * 4 + 3], w4.w, acc[i]);
            }
        }
    }
    #pragma unroll
    for (int i = 0; i < 16; i++) {
        u16 h = f2b(acc[i]), lo = f2b(acc[i] - b2f(h));
        size_t o = (size_t)b * 262144 + (size_t)(c0 + i) * 512 + n * 64 + k;
        UTh[o] = h; UTl[o] = lo;
    }
}

// ---------------------------------------------------------------------------
// Kernel 5: out[b] = PP1[b] @ Ucat[b] + b_mixer.  64x64 tiles, grid (8,32,2).
// ---------------------------------------------------------------------------
__global__ __launch_bounds__(256) void gemm_out_mfma(const u16* __restrict__ PPh,
                                                     const u16* __restrict__ UTh,
                                                     const u16* __restrict__ UTl,
                                                     const float* __restrict__ bias,
                                                     float* __restrict__ out) {
    __shared__ u16 lds[6144];   // A 64x32 + B 2x64x32
    const int b = blockIdx.z;
    const u16* A  = PPh + (size_t)b * 2048 * 512;
    const u16* Bh = UTh + (size_t)b * 512 * 512;
    const u16* Bl = UTl + (size_t)b * 512 * 512;
    f32x4 acc[2][2] = {};
    const int m0 = blockIdx.y * 64, n0 = blockIdx.x * 64;
    gemm_core_a1b2<64, 64>(A, Bh, Bl, m0, n0, lds, acc);
    const int t = threadIdx.x, lane = t & 63, w = t >> 6, wm = w & 1, wn = w >> 1;
    const int fr = lane & 15, q = lane >> 4;
    #pragma unroll
    for (int i = 0; i < 2; i++) {
        int m = m0 + wm * 32 + i * 16 + q * 4;
        #pragma unroll
        for (int j = 0; j < 2; j++) {
            int n = n0 + wn * 32 + j * 16 + fr;
            float bv = bias[n];
            #pragma unroll
            for (int r = 0; r < 4; r++)
                out[(size_t)(b * 2048 + m + r) * 512 + n] = acc[i][j][r] + bv;
        }
    }
}

// ---------------------------------------------------------------------------
extern "C" void kernel_launch(void* const* d_in, const int* in_sizes, int n_in,
                              void* d_out, int out_size, void* d_ws, size_t ws_size,
                              hipStream_t stream) {
    (void)in_sizes; (void)n_in; (void)out_size; (void)ws_size;
    const float* x1        = (const float*)d_in[0];
    const float* x2        = (const float*)d_in[1];
    const float* gamma     = (const float*)d_in[2];
    const float* beta      = (const float*)d_in[3];
    const float* proj      = (const float*)d_in[4];
    const float* halves    = (const float*)d_in[5];
    const float* diagonals = (const float*)d_in[6];
    const float* Wm        = (const float*)d_in[7];
    const float* bmix      = (const float*)d_in[8];
    float* out = (float*)d_out;

    u16* us    = (u16*)d_ws;
    u16* Xh    = us;                        // 4,194,304
    u16* Pwh   = Xh + 4194304;              // 262,144
    u16* Pwl   = Pwh + 262144;              // 262,144
    u16* PPh   = Pwl + 262144;              // 2,097,152 (x1 rows only, natural)
    u16* PPT1h = PPh + 2097152;             // 2,097,152 ([b][c][v])
    u16* PPT2h = PPT1h + 2097152;           // 2,097,152
    u16* UTh   = PPT2h + 2097152;           // 524,288
    u16* UTl   = UTh + 524288;              // 524,288
    float* S    = (float*)(UTl + 524288);   // 65,536 f
    float* Tbuf = S + 65536;                // 65,536 f

    ln_prep<<<dim3(8257), 256, 0, stream>>>(x1, x2, gamma, beta, proj, Xh, Pwh, Pwl, S);
    gemm_proj_mfma<<<dim3(8, 64), 256, 0, stream>>>(Xh, Pwh, Pwl, PPh, PPT1h, PPT2h);
    s_kernel<<<dim3(16, 8), 256, 0, stream>>>(PPT2h, PPT1h, S);
    tu_a<<<dim3(16, 4), 256, 0, stream>>>(S, halves, diagonals, Tbuf);
    tu_b<<<dim3(16, 8), 256, 0, stream>>>(Tbuf, Wm, UTh, UTl);
    gemm_out_mfma<<<dim3(8, 32, 2), 256, 0, stream>>>(PPh, UTh, UTl, bmix, out);
}

// Round 5
// 143.271 us; speedup vs baseline: 1.5985x; 1.0263x over previous
//
#include <hip/hip_runtime.h>

typedef unsigned short u16;
typedef __attribute__((ext_vector_type(8))) short short8;   // 8 x bf16 (4 VGPRs)
typedef __attribute__((ext_vector_type(4))) float f32x4;

#define HALFN 2016

__device__ __forceinline__ u16 f2b_rn(float x) {         // round-nearest-even
    union { float f; unsigned u; } v; v.f = x;
    unsigned r = v.u + 0x7FFFu + ((v.u >> 16) & 1u);
    return (u16)(r >> 16);
}

__device__ __forceinline__ void gll16(const void* g, void* s) {
    __builtin_amdgcn_global_load_lds(
        (const __attribute__((address_space(1))) unsigned int*)g,
        (__attribute__((address_space(3))) unsigned int*)s, 16, 0, 0);
}

// ---------------------------------------------------------------------------
// Kernel 1 (fused): blocks 0..8191 LayerNorm -> Xh (RN bf16);
// blocks 8192..8255 prep Pw (transpose, RN bf16); block 8256 zeroes S.
// ---------------------------------------------------------------------------
__global__ __launch_bounds__(256) void ln_prep(const float* __restrict__ x1,
                                               const float* __restrict__ x2,
                                               const float* __restrict__ gamma,
                                               const float* __restrict__ beta,
                                               const float* __restrict__ proj,
                                               u16* __restrict__ Xh,
                                               u16* __restrict__ Pwh,
                                               float* __restrict__ S) {
    __shared__ float ls[8], lq[8];
    __shared__ float tile[64][65];
    const int bid = blockIdx.x, t = threadIdx.x;

    if (bid < 8192) {
        const float* src = (bid < 4096) ? (x1 + (size_t)bid * 512)
                                        : (x2 + (size_t)(bid - 4096) * 512);
        float2 v = *(const float2*)&src[t * 2];
        float s  = v.x + v.y;
        float sq = v.x * v.x + v.y * v.y;
        #pragma unroll
        for (int off = 32; off > 0; off >>= 1) {
            s  += __shfl_down(s, off);
            sq += __shfl_down(sq, off);
        }
        int wave = t >> 6, lane = t & 63;
        if (lane == 0) { ls[wave] = s; lq[wave] = sq; }
        __syncthreads();
        if (t == 0) {
            float Sm = 0.f, Q = 0.f;
            #pragma unroll
            for (int i = 0; i < 4; i++) { Sm += ls[i]; Q += lq[i]; }
            float mu  = Sm * (1.0f / 512.0f);
            float var = Q * (1.0f / 512.0f) - mu * mu;
            ls[4] = mu;
            lq[4] = rsqrtf(var + 1e-5f);
        }
        __syncthreads();
        float mu = ls[4], rs = lq[4];
        float2 g  = *(const float2*)&gamma[t * 2];
        float2 bb = *(const float2*)&beta[t * 2];
        float o0 = (v.x - mu) * rs * g.x + bb.x;
        float o1 = (v.y - mu) * rs * g.y + bb.y;
        ushort2 H; H.x = f2b_rn(o0); H.y = f2b_rn(o1);
        *(ushort2*)&Xh[(size_t)bid * 512 + t * 2] = H;
    } else if (bid < 8256) {
        const int id = bid - 8192;
        const int n = id >> 3, c0 = (id & 7) * 64;
        #pragma unroll
        for (int i = 0; i < 4; i++) {
            int flat = i * 256 + t;
            int c = flat >> 4, k4 = (flat & 15) * 4;
            float4 v = *(const float4*)&proj[(size_t)n * 32768 + (size_t)(c0 + c) * 64 + k4];
            tile[c][k4 + 0] = v.x; tile[c][k4 + 1] = v.y;
            tile[c][k4 + 2] = v.z; tile[c][k4 + 3] = v.w;
        }
        __syncthreads();
        #pragma unroll
        for (int i = 0; i < 16; i++) {
            int flat = i * 256 + t;
            int k = flat >> 6, c = flat & 63;
            Pwh[(size_t)(n * 64 + k) * 512 + c0 + c] = f2b_rn(tile[c][k]);
        }
    } else {
        float4 z = {0.f, 0.f, 0.f, 0.f};
        #pragma unroll
        for (int i = 0; i < 64; i++)
            *(float4*)&S[(size_t)(i * 256 + t) * 4] = z;
    }
}

// ---------------------------------------------------------------------------
// MFMA single-product bf16 GEMM core: TMxTN tile, BK=32, K=512, ld=512.
// XOR-swizzled LDS, gll16 staging, conflict-free ds_read_b128 fragments.
// ---------------------------------------------------------------------------
template<int TM, int TN>
__device__ __forceinline__ void gemm_core_a1b1(const u16* __restrict__ A,
                                               const u16* __restrict__ B,
                                               int m0, int n0, u16* lds,
                                               f32x4 (&acc)[TM / 32][TN / 32]) {
    constexpr int MI = TM / 32, NI = TN / 32;
    constexpr int LA = TM * 32;
    const int t = threadIdx.x;
    const int lane = t & 63;
    const int w = t >> 6, wm = w & 1, wn = w >> 1;
    const int fr = lane & 15, q = lane >> 4;

    int aoff[MI], boff[NI];
    #pragma unroll
    for (int i = 0; i < MI; i++) {
        int r = wm * (TM / 2) + i * 16 + fr;
        aoff[i] = r * 32 + ((q ^ ((r >> 1) & 3)) * 8);
    }
    #pragma unroll
    for (int j = 0; j < NI; j++) {
        int r = wn * (TN / 2) + j * 16 + fr;
        boff[j] = r * 32 + ((q ^ ((r >> 1) & 3)) * 8);
    }

    for (int kt = 0; kt < 512; kt += 32) {
        #pragma unroll
        for (int p = 0; p < TM / 64; p++) {
            int o = p * 4096 + t * 16;
            int r = o >> 6;
            int kc = ((o >> 4) & 3) ^ ((r >> 1) & 3);
            gll16(A + (size_t)(m0 + r) * 512 + kt + kc * 8, lds + (o >> 1));
        }
        #pragma unroll
        for (int p = 0; p < TN / 64; p++) {
            int o = p * 4096 + t * 16;
            int r = o >> 6;
            int kc = ((o >> 4) & 3) ^ ((r >> 1) & 3);
            gll16(B + (size_t)(n0 + r) * 512 + kt + kc * 8, lds + LA + (o >> 1));
        }
        __syncthreads();
        short8 af[MI], bf[NI];
        #pragma unroll
        for (int i = 0; i < MI; i++)
            af[i] = *(const short8*)(lds + aoff[i]);
        #pragma unroll
        for (int j = 0; j < NI; j++)
            bf[j] = *(const short8*)(lds + LA + boff[j]);
        #pragma unroll
        for (int i = 0; i < MI; i++)
            #pragma unroll
            for (int j = 0; j < NI; j++)
                acc[i][j] = __builtin_amdgcn_mfma_f32_16x16x32_bf16(af[i], bf[j], acc[i][j], 0, 0, 0);
        __syncthreads();
    }
}

// ---------------------------------------------------------------------------
// Kernel 2: PP = Xn @ Pw (128x64 tiles, grid (8,64)=512 blocks).
// x1-half epilogue: PPh natural (RN) + PPT1h transposed (RN).
// x2-half epilogue: PPT2h transposed (RN) only.  PPT layout: [b][c(512)][v(2048)].
// ---------------------------------------------------------------------------
__global__ __launch_bounds__(256) void gemm_proj_mfma(const u16* __restrict__ Xh,
                                                      const u16* __restrict__ Pwh,
                                                      u16* __restrict__ PPh,
                                                      u16* __restrict__ PPT1h,
                                                      u16* __restrict__ PPT2h) {
    __shared__ u16 lds[6144];   // 128*32 + 64*32
    f32x4 acc[4][2] = {};
    const int m0 = blockIdx.y * 128, n0 = blockIdx.x * 64;
    gemm_core_a1b1<128, 64>(Xh, Pwh, m0, n0, lds, acc);
    const int t = threadIdx.x, lane = t & 63, w = t >> 6, wm = w & 1, wn = w >> 1;
    const int fr = lane & 15, q = lane >> 4;
    const int src2 = (m0 >= 4096);
    const int b = (m0 & 4095) >> 11;
    const int v00 = m0 & 2047;
    #pragma unroll
    for (int i = 0; i < 4; i++) {
        int mloc = wm * 64 + i * 16 + q * 4;
        int v = v00 + mloc;
        #pragma unroll
        for (int j = 0; j < 2; j++) {
            int n = n0 + wn * 32 + j * 16 + fr;
            u16 hs[4];
            #pragma unroll
            for (int r = 0; r < 4; r++) hs[r] = f2b_rn(acc[i][j][r]);
            ushort4 hv; hv.x = hs[0]; hv.y = hs[1]; hv.z = hs[2]; hv.w = hs[3];
            if (!src2) {
                #pragma unroll
                for (int r = 0; r < 4; r++)
                    PPh[(size_t)(m0 + mloc + r) * 512 + n] = hs[r];
                *(ushort4*)&PPT1h[((size_t)(b * 512 + n)) * 2048 + v] = hv;
            } else {
                *(ushort4*)&PPT2h[((size_t)(b * 512 + n)) * 2048 + v] = hv;
            }
        }
    }
}

// ---------------------------------------------------------------------------
// Kernel 3: G[b,n] = P2^T P1 via single-product MFMA over K=v.
// grid (16 bn, 16 v-splits of 128).  A=PPT2h rows j, B=PPT1h rows kk, ld=2048.
// ---------------------------------------------------------------------------
__global__ __launch_bounds__(256) void s_kernel(const u16* __restrict__ PPT2h,
                                                const u16* __restrict__ PPT1h,
                                                float* __restrict__ S) {
    __shared__ u16 lds[4096];   // A 64x32 + B 64x32
    const int bn = blockIdx.x, b = bn >> 3, n = bn & 7;
    const u16* A = PPT2h + ((size_t)(b * 512 + n * 64)) * 2048;
    const u16* B = PPT1h + ((size_t)(b * 512 + n * 64)) * 2048;
    const int t = threadIdx.x, lane = t & 63, w = t >> 6, wm = w & 1, wn = w >> 1;
    const int fr = lane & 15, q = lane >> 4;

    int aoff[2], boff[2];
    #pragma unroll
    for (int i = 0; i < 2; i++) {
        int r = wm * 32 + i * 16 + fr;
        aoff[i] = r * 32 + ((q ^ ((r >> 1) & 3)) * 8);
    }
    #pragma unroll
    for (int j = 0; j < 2; j++) {
        int r = wn * 32 + j * 16 + fr;
        boff[j] = r * 32 + ((q ^ ((r >> 1) & 3)) * 8);
    }
    const int o = t * 16;
    const int rr = o >> 6;
    const int kc = ((o >> 4) & 3) ^ ((rr >> 1) & 3);
    const int le = o >> 1;

    f32x4 acc[2][2] = {};
    const int k0 = blockIdx.y * 128;
    for (int kt = k0; kt < k0 + 128; kt += 32) {
        size_t g = (size_t)rr * 2048 + kt + kc * 8;
        gll16(A + g, lds + le);
        gll16(B + g, lds + 2048 + le);
        __syncthreads();
        short8 af[2], bf[2];
        #pragma unroll
        for (int i = 0; i < 2; i++) af[i] = *(const short8*)(lds + aoff[i]);
        #pragma unroll
        for (int j = 0; j < 2; j++) bf[j] = *(const short8*)(lds + 2048 + boff[j]);
        #pragma unroll
        for (int i = 0; i < 2; i++)
            #pragma unroll
            for (int j = 0; j < 2; j++)
                acc[i][j] = __builtin_amdgcn_mfma_f32_16x16x32_bf16(af[i], bf[j], acc[i][j], 0, 0, 0);
        __syncthreads();
    }
    float* Sb = S + (size_t)bn * 4096;
    #pragma unroll
    for (int i = 0; i < 2; i++) {
        int jrow = wm * 32 + i * 16 + q * 4;
        #pragma unroll
        for (int j = 0; j < 2; j++) {
            int kk = wn * 32 + j * 16 + fr;
            #pragma unroll
            for (int r = 0; r < 4; r++)
                atomicAdd(&Sb[(jrow + r) * 64 + kk], acc[i][j][r]);
        }
    }
}

// ---------------------------------------------------------------------------
// Kernel 4a: build metric M_n, T_bn = M @ G.  grid (16 bn, 4 l-chunks of 16).
// ---------------------------------------------------------------------------
__global__ __launch_bounds__(256) void tu_a(const float* __restrict__ S,
                                            const float* __restrict__ halves,
                                            const float* __restrict__ diagonals,
                                            float* __restrict__ Tbuf) {
    __shared__ float Ms[64][65];
    __shared__ float Gs[64][68];
    const int bn = blockIdx.x;
    const int n = bn & 7;
    const int t = threadIdx.x;

    for (int idx = t; idx < 4096; idx += 256) {
        int r = idx >> 6, c = idx & 63;
        float val;
        if (r == c) {
            val = diagonals[n * 64 + r];
        } else {
            int rr = (r < c) ? r : c;
            int cc = (r < c) ? c : r;
            int h = rr * 63 - (rr * (rr - 1)) / 2 + (cc - rr - 1);
            val = halves[n * HALFN + h];
        }
        Ms[r][c] = val;
    }
    for (int idx = t; idx < 4096; idx += 256) {
        Gs[idx >> 6][idx & 63] = S[(size_t)bn * 4096 + idx];
    }
    __syncthreads();

    const int k = t & 63, lq = t >> 6;
    const int l = blockIdx.y * 16 + lq * 4;
    float4 a = {0.f, 0.f, 0.f, 0.f};
    #pragma unroll 8
    for (int j = 0; j < 64; j++) {
        float m = Ms[k][j];
        float4 g = *(const float4*)&Gs[j][l];
        a.x = fmaf(m, g.x, a.x);
        a.y = fmaf(m, g.y, a.y);
        a.z = fmaf(m, g.z, a.z);
        a.w = fmaf(m, g.w, a.w);
    }
    *(float4*)&Tbuf[(size_t)bn * 4096 + k * 64 + l] = a;
}

// ---------------------------------------------------------------------------
// Kernel 4b: UT[b][c'][(n,k)] = sum_kk T_bn[k][kk] * Wm[c'][n*64+kk], RN bf16.
// grid (16 bn, 8 c-chunks of 64).
// ---------------------------------------------------------------------------
__global__ __launch_bounds__(256) void tu_b(const float* __restrict__ Tbuf,
                                            const float* __restrict__ Wm,
                                            u16* __restrict__ UTh) {
    __shared__ float Ts[64][68];
    const int bn = blockIdx.x, b = bn >> 3, n = bn & 7;
    const int t = threadIdx.x;
    #pragma unroll
    for (int i = 0; i < 4; i++) {
        int flat4 = i * 256 + t;
        int kk = flat4 >> 4, kk4 = (flat4 & 15) * 4;
        float4 v = *(const float4*)&Tbuf[(size_t)bn * 4096 + kk * 64 + kk4];
        int pos = (((kk4 >> 4) ^ (kk & 3)) * 16) + (kk4 & 15);
        *(float4*)&Ts[kk][pos] = v;
    }
    __syncthreads();

    const int k = t & 63, cg = t >> 6;
    const int c0 = blockIdx.y * 64 + cg * 16;
    float acc[16] = {};
    #pragma unroll
    for (int kkc = 0; kkc < 4; kkc++) {
        const float* tp = &Ts[k][(kkc ^ (k & 3)) * 16];
        float ts[16];
        #pragma unroll
        for (int u = 0; u < 4; u++) {
            float4 t4 = *(const float4*)&tp[u * 4];
            ts[u * 4 + 0] = t4.x; ts[u * 4 + 1] = t4.y;
            ts[u * 4 + 2] = t4.z; ts[u * 4 + 3] = t4.w;
        }
        #pragma unroll
        for (int i = 0; i < 16; i++) {
            const float* wrow = &Wm[(size_t)(c0 + i) * 512 + n * 64 + kkc * 16];
            #pragma unroll
            for (int u = 0; u < 4; u++) {
                float4 w4 = *(const float4*)&wrow[u * 4];
                acc[i] = fmaf(ts[u * 4 + 0], w4.x, acc[i]);
                acc[i] = fmaf(ts[u * 4 + 1], w4.y, acc[i]);
                acc[i] = fmaf(ts[u * 4 + 2], w4.z, acc[i]);
                acc[i] = fmaf(ts[u * 4 + 3], w4.w, acc[i]);
            }
        }
    }
    #pragma unroll
    for (int i = 0; i < 16; i++) {
        size_t o = (size_t)b * 262144 + (size_t)(c0 + i) * 512 + n * 64 + k;
        UTh[o] = f2b_rn(acc[i]);
    }
}

// ---------------------------------------------------------------------------
// Kernel 5: out[b] = PP1[b] @ Ucat[b] + b_mixer.  64x64 tiles, grid (8,32,2).
// ---------------------------------------------------------------------------
__global__ __launch_bounds__(256) void gemm_out_mfma(const u16* __restrict__ PPh,
                                                     const u16* __restrict__ UTh,
                                                     const float* __restrict__ bias,
                                                     float* __restrict__ out) {
    __shared__ u16 lds[4096];   // A 64x32 + B 64x32
    const int b = blockIdx.z;
    const u16* A = PPh + (size_t)b * 2048 * 512;
    const u16* B = UTh + (size_t)b * 512 * 512;
    f32x4 acc[2][2] = {};
    const int m0 = blockIdx.y * 64, n0 = blockIdx.x * 64;
    gemm_core_a1b1<64, 64>(A, B, m0, n0, lds, acc);
    const int t = threadIdx.x, lane = t & 63, w = t >> 6, wm = w & 1, wn = w >> 1;
    const int fr = lane & 15, q = lane >> 4;
    #pragma unroll
    for (int i = 0; i < 2; i++) {
        int m = m0 + wm * 32 + i * 16 + q * 4;
        #pragma unroll
        for (int j = 0; j < 2; j++) {
            int n = n0 + wn * 32 + j * 16 + fr;
            float bv = bias[n];
            #pragma unroll
            for (int r = 0; r < 4; r++)
                out[(size_t)(b * 2048 + m + r) * 512 + n] = acc[i][j][r] + bv;
        }
    }
}

// ---------------------------------------------------------------------------
extern "C" void kernel_launch(void* const* d_in, const int* in_sizes, int n_in,
                              void* d_out, int out_size, void* d_ws, size_t ws_size,
                              hipStream_t stream) {
    (void)in_sizes; (void)n_in; (void)out_size; (void)ws_size;
    const float* x1        = (const float*)d_in[0];
    const float* x2        = (const float*)d_in[1];
    const float* gamma     = (const float*)d_in[2];
    const float* beta      = (const float*)d_in[3];
    const float* proj      = (const float*)d_in[4];
    const float* halves    = (const float*)d_in[5];
    const float* diagonals = (const float*)d_in[6];
    const float* Wm        = (const float*)d_in[7];
    const float* bmix      = (const float*)d_in[8];
    float* out = (float*)d_out;

    u16* us    = (u16*)d_ws;
    u16* Xh    = us;                        // 4,194,304
    u16* Pwh   = Xh + 4194304;              // 262,144
    u16* PPh   = Pwh + 262144;              // 2,097,152 (x1 rows only, natural)
    u16* PPT1h = PPh + 2097152;             // 2,097,152 ([b][c][v])
    u16* PPT2h = PPT1h + 2097152;           // 2,097,152
    u16* UTh   = PPT2h + 2097152;           // 524,288
    float* S    = (float*)(UTh + 524288);   // 65,536 f
    float* Tbuf = S + 65536;                // 65,536 f

    ln_prep<<<dim3(8257), 256, 0, stream>>>(x1, x2, gamma, beta, proj, Xh, Pwh, S);
    gemm_proj_mfma<<<dim3(8, 64), 256, 0, stream>>>(Xh, Pwh, PPh, PPT1h, PPT2h);
    s_kernel<<<dim3(16, 16), 256, 0, stream>>>(PPT2h, PPT1h, S);
    tu_a<<<dim3(16, 4), 256, 0, stream>>>(S, halves, diagonals, Tbuf);
    tu_b<<<dim3(16, 8), 256, 0, stream>>>(Tbuf, Wm, UTh);
    gemm_out_mfma<<<dim3(8, 32, 2), 256, 0, stream>>>(PPh, UTh, bmix, out);
}